// Round 3
// baseline (56.503 us; speedup 1.0000x reference)
//
#include <hip/hip_runtime.h>
#include <hip/hip_cooperative_groups.h>
#include <math.h>

namespace cg = cooperative_groups;

// RMSPE loss with optimal source permutation (n=5).
// Assignment min via subset DP (Held-Karp), fully unrolled -> registers only.
// SINGLE cooperative dispatch: per-block partials -> grid sync -> block 0
// reduces. Plain stores only; every output byte overwritten every call.

#define NSRC 5

__device__ __forceinline__ float sample_rmspe(const float pr[NSRC], const float tg[NSRC]) {
    const float PI     = 3.14159265358979323846f;
    const float INV_PI = 0.31830988618379067154f;

    // c[i][j] = wrap(pred_i - tgt_j)^2, wrap into [-pi/2, pi/2)
    float c[NSRC][NSRC];
#pragma unroll
    for (int i = 0; i < NSRC; ++i) {
#pragma unroll
        for (int j = 0; j < NSRC; ++j) {
            float x = pr[i] - tg[j];
            // (x + pi/2) mod pi - pi/2  ==  x - pi*floor(x/pi + 0.5)
            float d = x - PI * floorf(fmaf(x, INV_PI, 0.5f));
            c[i][j] = d * d;
        }
    }

    // Held-Karp over column subsets: dp[mask] = min cost of assigning
    // rows 0..popcount(mask)-1 to the columns in `mask`. Fully unrolled,
    // all indices compile-time -> registers (no scratch).
    float dp[1 << NSRC];
    dp[0] = 0.0f;
#pragma unroll
    for (int mask = 1; mask < (1 << NSRC); ++mask) {
        const int i = __popc(mask) - 1;
        float best = 3.4e38f;
#pragma unroll
        for (int j = 0; j < NSRC; ++j) {
            if (mask & (1 << j)) {
                float cand = dp[mask ^ (1 << j)] + c[i][j];
                best = fminf(best, cand);
            }
        }
        dp[mask] = best;
    }
    return sqrtf(dp[(1 << NSRC) - 1] * (1.0f / NSRC));
}

__global__ __launch_bounds__(256) void rmspe_coop(const float4* __restrict__ pred4,
                                                  const float4* __restrict__ tgt4,
                                                  float* __restrict__ partial,
                                                  float* __restrict__ out,
                                                  int nquad, int B,
                                                  const float* __restrict__ pred,
                                                  const float* __restrict__ tgt) {
    float val = 0.0f;
    const int stride = gridDim.x * blockDim.x;
    for (int q = blockIdx.x * blockDim.x + threadIdx.x; q < nquad; q += stride) {
        const float4* pp = pred4 + (size_t)q * NSRC;
        const float4* tp = tgt4  + (size_t)q * NSRC;
        float4 p0 = pp[0], p1 = pp[1], p2 = pp[2], p3 = pp[3], p4 = pp[4];
        float4 t0 = tp[0], t1 = tp[1], t2 = tp[2], t3 = tp[3], t4 = tp[4];
        float pf[20] = {p0.x,p0.y,p0.z,p0.w, p1.x,p1.y,p1.z,p1.w,
                        p2.x,p2.y,p2.z,p2.w, p3.x,p3.y,p3.z,p3.w,
                        p4.x,p4.y,p4.z,p4.w};
        float tf[20] = {t0.x,t0.y,t0.z,t0.w, t1.x,t1.y,t1.z,t1.w,
                        t2.x,t2.y,t2.z,t2.w, t3.x,t3.y,t3.z,t3.w,
                        t4.x,t4.y,t4.z,t4.w};
#pragma unroll
        for (int s = 0; s < 4; ++s)
            val += sample_rmspe(&pf[s * NSRC], &tf[s * NSRC]);
    }

    // Scalar tail (B % 4 samples): first few global threads take one each.
    const int tail_start = nquad * 4;
    const int gtid = blockIdx.x * blockDim.x + threadIdx.x;
    if (tail_start + gtid < B) {
        float pr[NSRC], tg[NSRC];
#pragma unroll
        for (int i = 0; i < NSRC; ++i) {
            pr[i] = pred[(size_t)(tail_start + gtid) * NSRC + i];
            tg[i] = tgt [(size_t)(tail_start + gtid) * NSRC + i];
        }
        val += sample_rmspe(pr, tg);
    }

    // 64-lane wave reduction, then block reduction
#pragma unroll
    for (int off = 32; off > 0; off >>= 1)
        val += __shfl_down(val, off, 64);

    __shared__ float wsum[4];  // 256 threads = 4 waves
    const int lane = threadIdx.x & 63;
    const int wid  = threadIdx.x >> 6;
    if (lane == 0) wsum[wid] = val;
    __syncthreads();
    if (threadIdx.x == 0)
        partial[blockIdx.x] = wsum[0] + wsum[1] + wsum[2] + wsum[3];

    // Grid-wide barrier (device-scope fence), then block 0 finishes.
    cg::this_grid().sync();

    if (blockIdx.x == 0) {
        float v = 0.0f;
        for (int i = threadIdx.x; i < (int)gridDim.x; i += 256) v += partial[i];
#pragma unroll
        for (int off = 32; off > 0; off >>= 1)
            v += __shfl_down(v, off, 64);
        __shared__ float wsum2[4];
        if (lane == 0) wsum2[wid] = v;
        __syncthreads();
        if (threadIdx.x == 0)
            out[0] = wsum2[0] + wsum2[1] + wsum2[2] + wsum2[3];
    }
}

extern "C" void kernel_launch(void* const* d_in, const int* in_sizes, int n_in,
                              void* d_out, int out_size, void* d_ws, size_t ws_size,
                              hipStream_t stream) {
    const float* pred = (const float*)d_in[0];
    const float* tgt  = (const float*)d_in[1];
    float* out = (float*)d_out;
    float* partial = (float*)d_ws;

    int B = in_sizes[0] / NSRC;
    int nquad = B / 4;

    const int threads = 256;
    int blocks = (nquad + threads - 1) / threads;
    if (blocks > 512) blocks = 512;   // 2 blocks/CU -> co-residency guaranteed
    if (blocks < 1) blocks = 1;

    const float4* pred4 = (const float4*)pred;
    const float4* tgt4  = (const float4*)tgt;
    void* args[] = {(void*)&pred4, (void*)&tgt4, (void*)&partial, (void*)&out,
                    (void*)&nquad, (void*)&B, (void*)&pred, (void*)&tgt};
    hipLaunchCooperativeKernel((void*)rmspe_coop, dim3(blocks), dim3(threads),
                               args, 0, stream);
}

// Round 4
// 13.462 us; speedup vs baseline: 4.1972x; 4.1972x over previous
//
#include <hip/hip_runtime.h>
#include <math.h>

// RMSPE loss with optimal source permutation (n=5).
// Assignment min via subset DP (Held-Karp), fully unrolled -> registers only.
// Cost computed in (1/pi)-scaled space: c~[i][j] = (fract(u_i - v_j) - 0.5)^2
// where u = pred/pi + 0.5, v = tgt/pi; true cost = pi^2 * c~. The uniform
// pi^2 scale preserves the argmin, so it is folded into the final sqrt.
// Two-kernel reduction, plain stores only (no memset / atomics; every output
// byte overwritten every call).

#define NSRC 5

__device__ __forceinline__ float sample_dp(const float u[NSRC], const float v[NSRC]) {
    // c[i][j] = (fract(u_i - v_j) - 0.5)^2   [units of pi^2]
    float c[NSRC][NSRC];
#pragma unroll
    for (int i = 0; i < NSRC; ++i) {
#pragma unroll
        for (int j = 0; j < NSRC; ++j) {
            float t = u[i] - v[j];
            float g = __builtin_amdgcn_fractf(t) - 0.5f;   // t - floor(t) - 0.5
            c[i][j] = g * g;
        }
    }

    // Held-Karp over column subsets: dp[mask] = min cost of assigning
    // rows 0..popcount(mask)-1 to the columns in `mask`. Fully unrolled,
    // all indices compile-time -> registers only.
    float dp[1 << NSRC];
    dp[0] = 0.0f;
#pragma unroll
    for (int mask = 1; mask < (1 << NSRC); ++mask) {
        const int i = __popc(mask) - 1;
        float best = 3.4e38f;
#pragma unroll
        for (int j = 0; j < NSRC; ++j) {
            if (mask & (1 << j)) {
                float cand = dp[mask ^ (1 << j)] + c[i][j];
                best = fminf(best, cand);   // chains fuse to v_min3_f32
            }
        }
        dp[mask] = best;
    }
    return dp[(1 << NSRC) - 1];
}

// Kernel 1: each thread handles 4 samples (20 floats = 5 x float4, 16B-aligned
// since per-thread stride is 80B). One partial per block, plain store.
__global__ __launch_bounds__(256) void rmspe_partial(const float4* __restrict__ pred4,
                                                     const float4* __restrict__ tgt4,
                                                     float* __restrict__ partial,
                                                     int nquad, int B,
                                                     const float* __restrict__ pred,
                                                     const float* __restrict__ tgt) {
    const float INV_PI = 0.31830988618379067154f;
    const float PI2_OVER_N = 1.9739208802178717f;  // pi^2 / 5

    float val = 0.0f;
    const int stride = gridDim.x * blockDim.x;
    for (int q = blockIdx.x * blockDim.x + threadIdx.x; q < nquad; q += stride) {
        const float4* pp = pred4 + (size_t)q * NSRC;
        const float4* tp = tgt4  + (size_t)q * NSRC;
        float4 p0 = pp[0], p1 = pp[1], p2 = pp[2], p3 = pp[3], p4 = pp[4];
        float4 t0 = tp[0], t1 = tp[1], t2 = tp[2], t3 = tp[3], t4 = tp[4];
        float pf[20] = {p0.x,p0.y,p0.z,p0.w, p1.x,p1.y,p1.z,p1.w,
                        p2.x,p2.y,p2.z,p2.w, p3.x,p3.y,p3.z,p3.w,
                        p4.x,p4.y,p4.z,p4.w};
        float tf[20] = {t0.x,t0.y,t0.z,t0.w, t1.x,t1.y,t1.z,t1.w,
                        t2.x,t2.y,t2.z,t2.w, t3.x,t3.y,t3.z,t3.w,
                        t4.x,t4.y,t4.z,t4.w};
        // prescale: u = pred/pi + 0.5, v = tgt/pi
#pragma unroll
        for (int k = 0; k < 20; ++k) {
            pf[k] = fmaf(pf[k], INV_PI, 0.5f);
            tf[k] = tf[k] * INV_PI;
        }
#pragma unroll
        for (int s = 0; s < 4; ++s) {
            float m = sample_dp(&pf[s * NSRC], &tf[s * NSRC]);
            val += __builtin_amdgcn_sqrtf(m * PI2_OVER_N);
        }
    }

    // Scalar tail (B % 4 samples): first few global threads take one each.
    const int tail_start = nquad * 4;
    const int gtid = blockIdx.x * blockDim.x + threadIdx.x;
    if (tail_start + gtid < B) {
        float u[NSRC], v[NSRC];
#pragma unroll
        for (int i = 0; i < NSRC; ++i) {
            u[i] = fmaf(pred[(size_t)(tail_start + gtid) * NSRC + i], INV_PI, 0.5f);
            v[i] = tgt [(size_t)(tail_start + gtid) * NSRC + i] * INV_PI;
        }
        val += __builtin_amdgcn_sqrtf(sample_dp(u, v) * PI2_OVER_N);
    }

    // 64-lane wave reduction, then block reduction
#pragma unroll
    for (int off = 32; off > 0; off >>= 1)
        val += __shfl_down(val, off, 64);

    __shared__ float wsum[4];  // 256 threads = 4 waves
    const int lane = threadIdx.x & 63;
    const int wid  = threadIdx.x >> 6;
    if (lane == 0) wsum[wid] = val;
    __syncthreads();
    if (threadIdx.x == 0)
        partial[blockIdx.x] = wsum[0] + wsum[1] + wsum[2] + wsum[3];
}

// Kernel 2: ONE wave (64 threads) reduces the per-block partials.
// No LDS, no __syncthreads — pure shuffle. Plain store overwrites d_out.
__global__ __launch_bounds__(64) void rmspe_reduce(const float* __restrict__ partial,
                                                   int n, float* __restrict__ out) {
    float v = 0.0f;
    for (int i = threadIdx.x; i < n; i += 64) v += partial[i];
#pragma unroll
    for (int off = 32; off > 0; off >>= 1)
        v += __shfl_down(v, off, 64);
    if (threadIdx.x == 0) out[0] = v;
}

extern "C" void kernel_launch(void* const* d_in, const int* in_sizes, int n_in,
                              void* d_out, int out_size, void* d_ws, size_t ws_size,
                              hipStream_t stream) {
    const float* pred = (const float*)d_in[0];
    const float* tgt  = (const float*)d_in[1];
    float* out = (float*)d_out;
    float* partial = (float*)d_ws;

    const int B = in_sizes[0] / NSRC;
    const int nquad = B / 4;

    const int threads = 256;
    int blocks = (nquad + threads - 1) / threads;
    if (blocks > 512) blocks = 512;   // B=524288 -> exactly 512 blocks, 1 iter/thread
    if (blocks < 1) blocks = 1;

    rmspe_partial<<<blocks, threads, 0, stream>>>(
        (const float4*)pred, (const float4*)tgt, partial, nquad, B, pred, tgt);
    rmspe_reduce<<<1, 64, 0, stream>>>(partial, blocks, out);
}

// Round 5
// 12.596 us; speedup vs baseline: 4.4858x; 1.0688x over previous
//
#include <hip/hip_runtime.h>
#include <math.h>

// RMSPE loss with optimal source permutation (n=5).
// Assignment min via subset DP (Held-Karp), fully unrolled -> registers only.
// Cost computed in (1/pi)-scaled space: c~[i][j] = (fract(u_i - v_j) - 0.5)^2
// where u = pred/pi + 0.5, v = tgt/pi; true cost = pi^2 * c~. The uniform
// pi^2 scale preserves the argmin, so it is folded into the final sqrt.
// Two-dispatch reduction, plain stores only (no memset / atomics: every
// output byte is overwritten every call).
//
// Structure notes (measured this session):
//  - cg grid.sync() costs ~45 us on MI355X (R3) -> never use for this.
//  - in-graph hipMemsetAsync/fill dispatch costs ~35-40 us (R1) -> no atomics.
//  - two-dispatch graph has ~6-7 us fixed replay overhead; GPU work ~4 us.

#define NSRC 5

__device__ __forceinline__ float sample_dp(const float u[NSRC], const float v[NSRC]) {
    // c[i][j] = (fract(u_i - v_j) - 0.5)^2   [units of pi^2]
    float c[NSRC][NSRC];
#pragma unroll
    for (int i = 0; i < NSRC; ++i) {
#pragma unroll
        for (int j = 0; j < NSRC; ++j) {
            float t = u[i] - v[j];
            float g = __builtin_amdgcn_fractf(t) - 0.5f;   // t - floor(t) - 0.5
            c[i][j] = g * g;
        }
    }

    // Held-Karp over column subsets: dp[mask] = min cost of assigning
    // rows 0..popcount(mask)-1 to the columns in `mask`. Fully unrolled,
    // all indices compile-time -> registers only (no scratch).
    float dp[1 << NSRC];
    dp[0] = 0.0f;
#pragma unroll
    for (int mask = 1; mask < (1 << NSRC); ++mask) {
        const int i = __popc(mask) - 1;
        float best = 3.4e38f;
#pragma unroll
        for (int j = 0; j < NSRC; ++j) {
            if (mask & (1 << j)) {
                float cand = dp[mask ^ (1 << j)] + c[i][j];
                best = fminf(best, cand);   // chains fuse to v_min3_f32
            }
        }
        dp[mask] = best;
    }
    return dp[(1 << NSRC) - 1];
}

// Kernel 1: 1024-thread blocks, each thread handles 4 samples
// (20 floats = 5 x float4, 16B-aligned since per-thread stride is 80B).
// One partial per block, plain store.
__global__ __launch_bounds__(1024) void rmspe_partial(const float4* __restrict__ pred4,
                                                      const float4* __restrict__ tgt4,
                                                      float* __restrict__ partial,
                                                      int nquad, int B,
                                                      const float* __restrict__ pred,
                                                      const float* __restrict__ tgt) {
    const float INV_PI = 0.31830988618379067154f;
    const float PI2_OVER_N = 1.9739208802178717f;  // pi^2 / 5

    float val = 0.0f;
    const int stride = gridDim.x * blockDim.x;
    for (int q = blockIdx.x * blockDim.x + threadIdx.x; q < nquad; q += stride) {
        const float4* pp = pred4 + (size_t)q * NSRC;
        const float4* tp = tgt4  + (size_t)q * NSRC;
        float4 p0 = pp[0], p1 = pp[1], p2 = pp[2], p3 = pp[3], p4 = pp[4];
        float4 t0 = tp[0], t1 = tp[1], t2 = tp[2], t3 = tp[3], t4 = tp[4];
        float pf[20] = {p0.x,p0.y,p0.z,p0.w, p1.x,p1.y,p1.z,p1.w,
                        p2.x,p2.y,p2.z,p2.w, p3.x,p3.y,p3.z,p3.w,
                        p4.x,p4.y,p4.z,p4.w};
        float tf[20] = {t0.x,t0.y,t0.z,t0.w, t1.x,t1.y,t1.z,t1.w,
                        t2.x,t2.y,t2.z,t2.w, t3.x,t3.y,t3.z,t3.w,
                        t4.x,t4.y,t4.z,t4.w};
        // prescale: u = pred/pi + 0.5, v = tgt/pi
#pragma unroll
        for (int k = 0; k < 20; ++k) {
            pf[k] = fmaf(pf[k], INV_PI, 0.5f);
            tf[k] = tf[k] * INV_PI;
        }
#pragma unroll
        for (int s = 0; s < 4; ++s) {
            float m = sample_dp(&pf[s * NSRC], &tf[s * NSRC]);
            val += __builtin_amdgcn_sqrtf(m * PI2_OVER_N);
        }
    }

    // Scalar tail (B % 4 samples): first few global threads take one each.
    const int tail_start = nquad * 4;
    const int gtid = blockIdx.x * blockDim.x + threadIdx.x;
    if (tail_start + gtid < B) {
        float u[NSRC], v[NSRC];
#pragma unroll
        for (int i = 0; i < NSRC; ++i) {
            u[i] = fmaf(pred[(size_t)(tail_start + gtid) * NSRC + i], INV_PI, 0.5f);
            v[i] = tgt [(size_t)(tail_start + gtid) * NSRC + i] * INV_PI;
        }
        val += __builtin_amdgcn_sqrtf(sample_dp(u, v) * PI2_OVER_N);
    }

    // 64-lane wave reduction, then block reduction across 16 waves.
#pragma unroll
    for (int off = 32; off > 0; off >>= 1)
        val += __shfl_down(val, off, 64);

    __shared__ float wsum[16];  // 1024 threads = 16 waves
    const int lane = threadIdx.x & 63;
    const int wid  = threadIdx.x >> 6;
    if (lane == 0) wsum[wid] = val;
    __syncthreads();
    if (threadIdx.x == 0) {
        float s = 0.0f;
#pragma unroll
        for (int w = 0; w < 16; ++w) s += wsum[w];
        partial[blockIdx.x] = s;
    }
}

// Kernel 2: ONE wave reduces the per-block partials (n <= 512).
// No LDS, no __syncthreads — pure shuffle. Plain store overwrites d_out.
__global__ __launch_bounds__(64) void rmspe_reduce(const float* __restrict__ partial,
                                                   int n, float* __restrict__ out) {
    float v = 0.0f;
    for (int i = threadIdx.x; i < n; i += 64) v += partial[i];
#pragma unroll
    for (int off = 32; off > 0; off >>= 1)
        v += __shfl_down(v, off, 64);
    if (threadIdx.x == 0) out[0] = v;
}

extern "C" void kernel_launch(void* const* d_in, const int* in_sizes, int n_in,
                              void* d_out, int out_size, void* d_ws, size_t ws_size,
                              hipStream_t stream) {
    const float* pred = (const float*)d_in[0];
    const float* tgt  = (const float*)d_in[1];
    float* out = (float*)d_out;
    float* partial = (float*)d_ws;

    const int B = in_sizes[0] / NSRC;
    const int nquad = B / 4;

    const int threads = 1024;
    int blocks = (nquad + threads - 1) / threads;   // B=524288 -> 128 blocks
    if (blocks > 512) blocks = 512;
    if (blocks < 1) blocks = 1;

    rmspe_partial<<<blocks, threads, 0, stream>>>(
        (const float4*)pred, (const float4*)tgt, partial, nquad, B, pred, tgt);
    rmspe_reduce<<<1, 64, 0, stream>>>(partial, blocks, out);
}

// Round 6
// 11.013 us; speedup vs baseline: 5.1304x; 1.1437x over previous
//
#include <hip/hip_runtime.h>
#include <math.h>

// RMSPE loss with optimal source permutation (n=5).
// Assignment min via subset DP (Held-Karp), fully unrolled -> registers only.
// Cost computed in (1/pi)-scaled space: c~[i][j] = (fract(u_i - v_j) - 0.5)^2
// where u = pred/pi + 0.5, v = tgt/pi; true cost = pi^2 * c~. The uniform
// pi^2 scale preserves the argmin, so it is folded into the final sqrt.
// Two-dispatch reduction, plain stores only.
//
// Structure notes (measured this session):
//  - cg grid.sync() costs ~45 us on MI355X (R3) -> never use here.
//  - in-graph hipMemsetAsync fill dispatch ~25-40 us (R1) -> no atomics into d_out.
//  - last-block counter schemes are unsafe: d_ws is poisoned 0xAA once and
//    never re-poisoned between graph replays -> counter base is unknowable.
//  - two-dispatch graph: ~4 us GPU work + ~7 us fixed replay overhead.
//  - k1 is HBM-bound (21 MB / 6.3 TB/s = 3.3 us cold, ~2 us L2-warm);
//    VALU ~1.6 us -> further math trimming does not move the needle.

#define NSRC 5

__device__ __forceinline__ float sample_dp(const float u[NSRC], const float v[NSRC]) {
    // c[i][j] = (fract(u_i - v_j) - 0.5)^2   [units of pi^2]
    float c[NSRC][NSRC];
#pragma unroll
    for (int i = 0; i < NSRC; ++i) {
#pragma unroll
        for (int j = 0; j < NSRC; ++j) {
            float t = u[i] - v[j];
            float g = __builtin_amdgcn_fractf(t) - 0.5f;   // t - floor(t) - 0.5
            c[i][j] = g * g;
        }
    }

    // Held-Karp over column subsets: dp[mask] = min cost of assigning
    // rows 0..popcount(mask)-1 to the columns in `mask`. Fully unrolled,
    // all indices compile-time -> registers only (no scratch).
    float dp[1 << NSRC];
    dp[0] = 0.0f;
#pragma unroll
    for (int mask = 1; mask < (1 << NSRC); ++mask) {
        const int i = __popc(mask) - 1;
        float best = 3.4e38f;
#pragma unroll
        for (int j = 0; j < NSRC; ++j) {
            if (mask & (1 << j)) {
                float cand = dp[mask ^ (1 << j)] + c[i][j];
                best = fminf(best, cand);   // min chains fuse to v_min3_f32
            }
        }
        dp[mask] = best;
    }
    return dp[(1 << NSRC) - 1];
}

// Kernel 1: 512 blocks x 256 threads, each thread handles exactly 4 samples
// (20 floats = 5 x float4, 16B-aligned since per-thread stride is 80B).
// One partial per block, plain store.
__global__ __launch_bounds__(256) void rmspe_partial(const float4* __restrict__ pred4,
                                                     const float4* __restrict__ tgt4,
                                                     float* __restrict__ partial,
                                                     int nquad, int B,
                                                     const float* __restrict__ pred,
                                                     const float* __restrict__ tgt) {
    const float INV_PI = 0.31830988618379067154f;
    const float PI2_OVER_N = 1.9739208802178717f;  // pi^2 / 5

    float val = 0.0f;
    const int stride = gridDim.x * blockDim.x;
    for (int q = blockIdx.x * blockDim.x + threadIdx.x; q < nquad; q += stride) {
        const float4* pp = pred4 + (size_t)q * NSRC;
        const float4* tp = tgt4  + (size_t)q * NSRC;
        float4 p0 = pp[0], p1 = pp[1], p2 = pp[2], p3 = pp[3], p4 = pp[4];
        float4 t0 = tp[0], t1 = tp[1], t2 = tp[2], t3 = tp[3], t4 = tp[4];
        float pf[20] = {p0.x,p0.y,p0.z,p0.w, p1.x,p1.y,p1.z,p1.w,
                        p2.x,p2.y,p2.z,p2.w, p3.x,p3.y,p3.z,p3.w,
                        p4.x,p4.y,p4.z,p4.w};
        float tf[20] = {t0.x,t0.y,t0.z,t0.w, t1.x,t1.y,t1.z,t1.w,
                        t2.x,t2.y,t2.z,t2.w, t3.x,t3.y,t3.z,t3.w,
                        t4.x,t4.y,t4.z,t4.w};
        // prescale: u = pred/pi + 0.5, v = tgt/pi
#pragma unroll
        for (int k = 0; k < 20; ++k) {
            pf[k] = fmaf(pf[k], INV_PI, 0.5f);
            tf[k] = tf[k] * INV_PI;
        }
#pragma unroll
        for (int s = 0; s < 4; ++s) {
            float m = sample_dp(&pf[s * NSRC], &tf[s * NSRC]);
            val += __builtin_amdgcn_sqrtf(m * PI2_OVER_N);
        }
    }

    // Scalar tail (B % 4 samples): first few global threads take one each.
    const int tail_start = nquad * 4;
    const int gtid = blockIdx.x * blockDim.x + threadIdx.x;
    if (tail_start + gtid < B) {
        float u[NSRC], v[NSRC];
#pragma unroll
        for (int i = 0; i < NSRC; ++i) {
            u[i] = fmaf(pred[(size_t)(tail_start + gtid) * NSRC + i], INV_PI, 0.5f);
            v[i] = tgt [(size_t)(tail_start + gtid) * NSRC + i] * INV_PI;
        }
        val += __builtin_amdgcn_sqrtf(sample_dp(u, v) * PI2_OVER_N);
    }

    // 64-lane wave reduction, then block reduction.
#pragma unroll
    for (int off = 32; off > 0; off >>= 1)
        val += __shfl_down(val, off, 64);

    __shared__ float wsum[4];  // 256 threads = 4 waves
    const int lane = threadIdx.x & 63;
    const int wid  = threadIdx.x >> 6;
    if (lane == 0) wsum[wid] = val;
    __syncthreads();
    if (threadIdx.x == 0)
        partial[blockIdx.x] = wsum[0] + wsum[1] + wsum[2] + wsum[3];
}

// Kernel 2: one 256-thread block reduces the 512 partials (2 loads/thread).
// Plain store overwrites d_out every call.
__global__ __launch_bounds__(256) void rmspe_reduce(const float* __restrict__ partial,
                                                    int n, float* __restrict__ out) {
    float v = 0.0f;
    for (int i = threadIdx.x; i < n; i += 256) v += partial[i];
#pragma unroll
    for (int off = 32; off > 0; off >>= 1)
        v += __shfl_down(v, off, 64);
    __shared__ float wsum[4];
    const int lane = threadIdx.x & 63;
    const int wid  = threadIdx.x >> 6;
    if (lane == 0) wsum[wid] = v;
    __syncthreads();
    if (threadIdx.x == 0)
        out[0] = wsum[0] + wsum[1] + wsum[2] + wsum[3];
}

extern "C" void kernel_launch(void* const* d_in, const int* in_sizes, int n_in,
                              void* d_out, int out_size, void* d_ws, size_t ws_size,
                              hipStream_t stream) {
    const float* pred = (const float*)d_in[0];
    const float* tgt  = (const float*)d_in[1];
    float* out = (float*)d_out;
    float* partial = (float*)d_ws;

    const int B = in_sizes[0] / NSRC;
    const int nquad = B / 4;

    const int threads = 256;
    int blocks = (nquad + threads - 1) / threads;   // B=524288 -> exactly 512
    if (blocks > 512) blocks = 512;
    if (blocks < 1) blocks = 1;

    rmspe_partial<<<blocks, threads, 0, stream>>>(
        (const float4*)pred, (const float4*)tgt, partial, nquad, B, pred, tgt);
    rmspe_reduce<<<1, threads, 0, stream>>>(partial, blocks, out);
}